// Round 2
// baseline (19031.641 us; speedup 1.0000x reference)
//
#include <hip/hip_runtime.h>
#include <math.h>

// Problem constants (fixed by reference)
#define CCH   64      // channels
#define GG    192     // 3*C gates
#define SEQ   512     // encoder steps
#define DECS  35      // decoder steps
#define BT    8       // batch rows per workgroup
#define NTH   256     // 4 waves
#define HSTR  68      // h row stride (floats): 16B-aligned, conflict-free for b128
#define PSTR  260     // preact row stride (floats), mod32 = 4

// LDS layout (float offsets)
#define OFF_WT0   0                       // Whh layer0  [192][64] swizzled
#define OFF_WT1   12288                   // Wih layer1
#define OFF_WT2   24576                   // Whh layer1
#define OFF_HS0   36864                   // h0 [8][68]
#define OFF_HS1   (OFF_HS0 + BT*HSTR)     // 37408
#define OFF_PRE   (OFF_HS1 + BT*HSTR)     // 37952: pre [8][260]; [b][g<192]=r,z sums / gi_n; [b][192+c]=gh_n
#define OFF_EMB   (OFF_PRE + BT*PSTR)     // 40032
#define LDS_FLOATS (OFF_EMB + CCH)        // 40096
#define LDS_BYTES  (LDS_FLOATS * 4)       // 160384 <= 163840

__device__ __forceinline__ float sigf(float x) {
  return 1.0f / (1.0f + __expf(-x));
}
__device__ __forceinline__ float tanhfast(float x) {
  float t = __expf(-2.0f * fabsf(x));
  float r = (1.0f - t) / (1.0f + t);
  return copysignf(r, x);
}
__device__ __forceinline__ float dot4(float4 a, float4 b) {
  return a.x * b.x + a.y * b.y + a.z * b.z + a.w * b.w;
}

// Wave w owns gates [48w, 48w+48) for all 8 rows.
// Lane l: sub=l&15, bq=l>>4; gates g_j = 48w + 16j + sub (j=0..2); rows b0=2bq, b1=2bq+1.
// Weights stored stride-64 with chunk swizzle: float4 chunk kq of row g at chunk (kq ^ (g&15)).
// Since g_j & 15 == sub for all j, the read index is kq^sub, shared across j — and the
// 16 distinct rows per load land on distinct bank groups (<=2-way, free).
extern "C" __global__ void __launch_bounds__(NTH, 1)
gru_kernel(const float* __restrict__ pulse,   // [B,512,2]
           const float* __restrict__ d1w,     // [64,2]
           const float* __restrict__ d1b,     // [64]
           const float* __restrict__ d2w,     // [2,64]
           const float* __restrict__ d2b,     // [2]
           const float* __restrict__ Wih,     // [2,192,64]
           const float* __restrict__ Whh,     // [2,192,64]
           const float* __restrict__ bih,     // [2,192]
           const float* __restrict__ bhh,     // [2,192]
           const float* __restrict__ embed,   // [1,64]
           float* __restrict__ out)           // [B,35,2]
{
  extern __shared__ float lds[];
  const int tid = threadIdx.x;
  const int w   = tid >> 6;
  const int l   = tid & 63;
  const int sub = l & 15;
  const int bq  = l >> 4;
  const int b0  = bq * 2, b1 = bq * 2 + 1;

  float* WT0  = lds + OFF_WT0;
  float* WT1  = lds + OFF_WT1;
  float* WT2  = lds + OFF_WT2;
  float* hs0  = lds + OFF_HS0;
  float* hs1  = lds + OFF_HS1;
  float* pre  = lds + OFF_PRE;
  float* embs = lds + OFF_EMB;

  // ---- startup 1: fold dense1 into layer0 input gates. As[g][4] scratch in pre region.
  float* As = pre;
  if (tid < GG) {
    float a0 = 0.f, a1 = 0.f, cc = 0.f;
    for (int c = 0; c < CCH; ++c) {
      float wv = Wih[tid * CCH + c];
      a0 += wv * d1w[2 * c];
      a1 += wv * d1w[2 * c + 1];
      cc += wv * d1b[c];
    }
    As[tid * 4 + 0] = a0;
    As[tid * 4 + 1] = a1;
    As[tid * 4 + 2] = cc + bih[tid];
  }
  __syncthreads();

  int g_[3], rb_[3];
  bool isn_[3];
  float a0_[3], a1_[3], c0_[3], bhh0_[3], bih1_[3], bhh1_[3], bih0_[3];
#pragma unroll
  for (int j = 0; j < 3; ++j) {
    int g = 48 * w + 16 * j + sub;
    g_[j] = g; rb_[j] = g * CCH; isn_[j] = (g >= 128);
    a0_[j] = As[g * 4 + 0];
    a1_[j] = As[g * 4 + 1];
    c0_[j] = As[g * 4 + 2];
    bhh0_[j] = bhh[g];
    bih1_[j] = bih[GG + g];
    bhh1_[j] = bhh[GG + g];
    bih0_[j] = bih[g];
  }
  // nonlinearity-phase mapping
  const int nb = tid >> 5;          // row 0..7
  const int c1 = tid & 31, c2 = c1 + 32;
  const float d2w0a = d2w[c1], d2w0b = d2w[c2];
  const float d2w1a = d2w[CCH + c1], d2w1b = d2w[CCH + c2];
  const float d2b0 = d2b[0], d2b1 = d2b[1];
  __syncthreads();

  // ---- startup 2: stage swizzled weights, zero h, load embed
  for (int idx = tid; idx < GG * CCH; idx += NTH) {
    int g = idx >> 6, k = idx & 63;
    int kq = k >> 2, r = k & 3;
    int dst = g * CCH + (((kq ^ (g & 15)) << 2) | r);
    WT0[dst] = Whh[idx];
    WT1[dst] = Wih[GG * CCH + idx];
    WT2[dst] = Whh[GG * CCH + idx];
  }
  for (int i = tid; i < 2 * BT * HSTR; i += NTH) hs0[i] = 0.f;
  if (tid < CCH) embs[tid] = embed[tid];
  __syncthreads();

  const float4* W0j[3];
  const float4* W1j[3];
  const float4* W2j[3];
#pragma unroll
  for (int j = 0; j < 3; ++j) {
    W0j[j] = (const float4*)(WT0 + rb_[j]);
    W1j[j] = (const float4*)(WT1 + rb_[j]);
    W2j[j] = (const float4*)(WT2 + rb_[j]);
  }
  const float4* H0b0 = (const float4*)(hs0 + b0 * HSTR);
  const float4* H0b1 = (const float4*)(hs0 + b1 * HSTR);
  const float4* H1b0 = (const float4*)(hs1 + b0 * HSTR);
  const float4* H1b1 = (const float4*)(hs1 + b1 * HSTR);

  const int bgb = blockIdx.x * BT;
  const float* pu0 = pulse + (size_t)(bgb + b0) * SEQ * 2;
  const float* pu1 = pulse + (size_t)(bgb + b1) * SEQ * 2;
  float2 pc0 = *(const float2*)(pu0);
  float2 pc1 = *(const float2*)(pu1);

  // ======================= encoder: 512 steps =======================
  for (int t = 0; t < SEQ; ++t) {
    // prefetch next pulse (hidden under phase A)
    float2 pn0 = pc0, pn1 = pc1;
    if (t + 1 < SEQ) {
      pn0 = *(const float2*)(pu0 + (t + 1) * 2);
      pn1 = *(const float2*)(pu1 + (t + 1) * 2);
    }

    // phase A: gh0 = Whh0_q @ h0 (wave's 48-gate quarter, both rows)
    float accH[3][2] = {{0.f,0.f},{0.f,0.f},{0.f,0.f}};
#pragma unroll
    for (int kq = 0; kq < 16; ++kq) {
      int ix = kq ^ sub;
      float4 h0 = H0b0[kq];
      float4 h1 = H0b1[kq];
#pragma unroll
      for (int j = 0; j < 3; ++j) {
        float4 wv = W0j[j][ix];
        accH[j][0] += dot4(wv, h0);
        accH[j][1] += dot4(wv, h1);
      }
    }
#pragma unroll
    for (int j = 0; j < 3; ++j) {
      float gib0 = pc0.x * a0_[j] + pc0.y * a1_[j] + c0_[j];
      float gib1 = pc1.x * a0_[j] + pc1.y * a1_[j] + c0_[j];
      if (!isn_[j]) {  // r,z: store gi+gh sum
        pre[b0 * PSTR + g_[j]] = accH[j][0] + bhh0_[j] + gib0;
        pre[b1 * PSTR + g_[j]] = accH[j][1] + bhh0_[j] + gib1;
      } else {         // n: keep gi and gh separate
        pre[b0 * PSTR + g_[j]] = gib0;
        pre[b1 * PSTR + g_[j]] = gib1;
        pre[b0 * PSTR + g_[j] + 64] = accH[j][0] + bhh0_[j];
        pre[b1 * PSTR + g_[j] + 64] = accH[j][1] + bhh0_[j];
      }
    }
    __syncthreads();

    // phase B: layer0 nonlinearity -> hs0
    {
      float r1 = sigf(pre[nb * PSTR + c1]);
      float z1 = sigf(pre[nb * PSTR + 64 + c1]);
      float n1 = tanhfast(pre[nb * PSTR + 128 + c1] + r1 * pre[nb * PSTR + 192 + c1]);
      float r2 = sigf(pre[nb * PSTR + c2]);
      float z2 = sigf(pre[nb * PSTR + 64 + c2]);
      float n2 = tanhfast(pre[nb * PSTR + 128 + c2] + r2 * pre[nb * PSTR + 192 + c2]);
      float ho1 = hs0[nb * HSTR + c1], ho2 = hs0[nb * HSTR + c2];
      hs0[nb * HSTR + c1] = (1.0f - z1) * n1 + z1 * ho1;
      hs0[nb * HSTR + c2] = (1.0f - z2) * n2 + z2 * ho2;
    }
    __syncthreads();

    // phase C: gi1 = Wih1_q @ h0new ; gh1 = Whh1_q @ h1
    float accI[3][2] = {{0.f,0.f},{0.f,0.f},{0.f,0.f}};
    float accG[3][2] = {{0.f,0.f},{0.f,0.f},{0.f,0.f}};
#pragma unroll
    for (int kq = 0; kq < 16; ++kq) {
      int ix = kq ^ sub;
      float4 x0 = H0b0[kq];
      float4 x1 = H0b1[kq];
      float4 h0 = H1b0[kq];
      float4 h1 = H1b1[kq];
#pragma unroll
      for (int j = 0; j < 3; ++j) {
        float4 wi = W1j[j][ix];
        float4 wh = W2j[j][ix];
        accI[j][0] += dot4(wi, x0);
        accI[j][1] += dot4(wi, x1);
        accG[j][0] += dot4(wh, h0);
        accG[j][1] += dot4(wh, h1);
      }
    }
#pragma unroll
    for (int j = 0; j < 3; ++j) {
      if (!isn_[j]) {
        pre[b0 * PSTR + g_[j]] = accI[j][0] + accG[j][0] + bih1_[j] + bhh1_[j];
        pre[b1 * PSTR + g_[j]] = accI[j][1] + accG[j][1] + bih1_[j] + bhh1_[j];
      } else {
        pre[b0 * PSTR + g_[j]] = accI[j][0] + bih1_[j];
        pre[b1 * PSTR + g_[j]] = accI[j][1] + bih1_[j];
        pre[b0 * PSTR + g_[j] + 64] = accG[j][0] + bhh1_[j];
        pre[b1 * PSTR + g_[j] + 64] = accG[j][1] + bhh1_[j];
      }
    }
    __syncthreads();

    // phase D: layer1 nonlinearity -> hs1
    {
      float r1 = sigf(pre[nb * PSTR + c1]);
      float z1 = sigf(pre[nb * PSTR + 64 + c1]);
      float n1 = tanhfast(pre[nb * PSTR + 128 + c1] + r1 * pre[nb * PSTR + 192 + c1]);
      float r2 = sigf(pre[nb * PSTR + c2]);
      float z2 = sigf(pre[nb * PSTR + 64 + c2]);
      float n2 = tanhfast(pre[nb * PSTR + 128 + c2] + r2 * pre[nb * PSTR + 192 + c2]);
      float ho1 = hs1[nb * HSTR + c1], ho2 = hs1[nb * HSTR + c2];
      hs1[nb * HSTR + c1] = (1.0f - z1) * n1 + z1 * ho1;
      hs1[nb * HSTR + c2] = (1.0f - z2) * n2 + z2 * ho2;
    }
    __syncthreads();

    pc0 = pn0; pc1 = pn1;
  }

  // ======================= decoder: 35 steps =======================
  for (int d = 0; d < DECS; ++d) {
    // phase A: gi0 = Wih0_q @ x (global weights) ; gh0 = Whh0_q @ h0 (LDS)
    float accI[3][2] = {{0.f,0.f},{0.f,0.f},{0.f,0.f}};
    float accG[3][2] = {{0.f,0.f},{0.f,0.f},{0.f,0.f}};
    const float4* X0 = (d == 0) ? (const float4*)embs : H1b0;
    const float4* X1 = (d == 0) ? (const float4*)embs : H1b1;
#pragma unroll 4
    for (int kq = 0; kq < 16; ++kq) {
      int ix = kq ^ sub;
      float4 x0 = X0[kq];
      float4 x1 = X1[kq];
      float4 h0 = H0b0[kq];
      float4 h1 = H0b1[kq];
#pragma unroll
      for (int j = 0; j < 3; ++j) {
        float4 wg = *(const float4*)(Wih + rb_[j] + kq * 4);  // layer0 Wih, global (L1/L2-hot)
        float4 wh = W0j[j][ix];
        accI[j][0] += dot4(wg, x0);
        accI[j][1] += dot4(wg, x1);
        accG[j][0] += dot4(wh, h0);
        accG[j][1] += dot4(wh, h1);
      }
    }
#pragma unroll
    for (int j = 0; j < 3; ++j) {
      if (!isn_[j]) {
        pre[b0 * PSTR + g_[j]] = accI[j][0] + accG[j][0] + bih0_[j] + bhh0_[j];
        pre[b1 * PSTR + g_[j]] = accI[j][1] + accG[j][1] + bih0_[j] + bhh0_[j];
      } else {
        pre[b0 * PSTR + g_[j]] = accI[j][0] + bih0_[j];
        pre[b1 * PSTR + g_[j]] = accI[j][1] + bih0_[j];
        pre[b0 * PSTR + g_[j] + 64] = accG[j][0] + bhh0_[j];
        pre[b1 * PSTR + g_[j] + 64] = accG[j][1] + bhh0_[j];
      }
    }
    __syncthreads();

    // phase B: layer0 nonlinearity -> hs0
    {
      float r1 = sigf(pre[nb * PSTR + c1]);
      float z1 = sigf(pre[nb * PSTR + 64 + c1]);
      float n1 = tanhfast(pre[nb * PSTR + 128 + c1] + r1 * pre[nb * PSTR + 192 + c1]);
      float r2 = sigf(pre[nb * PSTR + c2]);
      float z2 = sigf(pre[nb * PSTR + 64 + c2]);
      float n2 = tanhfast(pre[nb * PSTR + 128 + c2] + r2 * pre[nb * PSTR + 192 + c2]);
      float ho1 = hs0[nb * HSTR + c1], ho2 = hs0[nb * HSTR + c2];
      hs0[nb * HSTR + c1] = (1.0f - z1) * n1 + z1 * ho1;
      hs0[nb * HSTR + c2] = (1.0f - z2) * n2 + z2 * ho2;
    }
    __syncthreads();

    // phase C: gi1, gh1
    float acc2I[3][2] = {{0.f,0.f},{0.f,0.f},{0.f,0.f}};
    float acc2G[3][2] = {{0.f,0.f},{0.f,0.f},{0.f,0.f}};
#pragma unroll
    for (int kq = 0; kq < 16; ++kq) {
      int ix = kq ^ sub;
      float4 x0 = H0b0[kq];
      float4 x1 = H0b1[kq];
      float4 h0 = H1b0[kq];
      float4 h1 = H1b1[kq];
#pragma unroll
      for (int j = 0; j < 3; ++j) {
        float4 wi = W1j[j][ix];
        float4 wh = W2j[j][ix];
        acc2I[j][0] += dot4(wi, x0);
        acc2I[j][1] += dot4(wi, x1);
        acc2G[j][0] += dot4(wh, h0);
        acc2G[j][1] += dot4(wh, h1);
      }
    }
#pragma unroll
    for (int j = 0; j < 3; ++j) {
      if (!isn_[j]) {
        pre[b0 * PSTR + g_[j]] = acc2I[j][0] + acc2G[j][0] + bih1_[j] + bhh1_[j];
        pre[b1 * PSTR + g_[j]] = acc2I[j][1] + acc2G[j][1] + bih1_[j] + bhh1_[j];
      } else {
        pre[b0 * PSTR + g_[j]] = acc2I[j][0] + bih1_[j];
        pre[b1 * PSTR + g_[j]] = acc2I[j][1] + bih1_[j];
        pre[b0 * PSTR + g_[j] + 64] = acc2G[j][0] + bhh1_[j];
        pre[b1 * PSTR + g_[j] + 64] = acc2G[j][1] + bhh1_[j];
      }
    }
    __syncthreads();

    // phase D: layer1 nonlinearity -> hs1, dense2 head -> out
    {
      float r1 = sigf(pre[nb * PSTR + c1]);
      float z1 = sigf(pre[nb * PSTR + 64 + c1]);
      float n1 = tanhfast(pre[nb * PSTR + 128 + c1] + r1 * pre[nb * PSTR + 192 + c1]);
      float r2 = sigf(pre[nb * PSTR + c2]);
      float z2 = sigf(pre[nb * PSTR + 64 + c2]);
      float n2 = tanhfast(pre[nb * PSTR + 128 + c2] + r2 * pre[nb * PSTR + 192 + c2]);
      float ho1 = hs1[nb * HSTR + c1], ho2 = hs1[nb * HSTR + c2];
      float h1n1 = (1.0f - z1) * n1 + z1 * ho1;
      float h1n2 = (1.0f - z2) * n2 + z2 * ho2;
      hs1[nb * HSTR + c1] = h1n1;
      hs1[nb * HSTR + c2] = h1n2;

      float o0 = h1n1 * d2w0a + h1n2 * d2w0b;
      float o1 = h1n1 * d2w1a + h1n2 * d2w1b;
#pragma unroll
      for (int off = 16; off >= 1; off >>= 1) {
        o0 += __shfl_xor(o0, off, 32);
        o1 += __shfl_xor(o1, off, 32);
      }
      if (c1 == 0) {
        out[((size_t)(bgb + nb) * DECS + d) * 2 + 0] = o0 + d2b0;
        out[((size_t)(bgb + nb) * DECS + d) * 2 + 1] = o1 + d2b1;
      }
    }
    __syncthreads();
  }
}

extern "C" void kernel_launch(void* const* d_in, const int* in_sizes, int n_in,
                              void* d_out, int out_size, void* d_ws, size_t ws_size,
                              hipStream_t stream) {
  const float* pulse = (const float*)d_in[0];
  const float* d1w   = (const float*)d_in[1];
  const float* d1b   = (const float*)d_in[2];
  const float* d2w   = (const float*)d_in[3];
  const float* d2b   = (const float*)d_in[4];
  const float* Wih   = (const float*)d_in[5];
  const float* Whh   = (const float*)d_in[6];
  const float* bih   = (const float*)d_in[7];
  const float* bhh   = (const float*)d_in[8];
  const float* emb   = (const float*)d_in[9];
  float* out = (float*)d_out;

  int B = in_sizes[0] / (SEQ * 2);   // 2048
  hipFuncSetAttribute((const void*)gru_kernel,
                      hipFuncAttributeMaxDynamicSharedMemorySize, LDS_BYTES);
  gru_kernel<<<B / BT, NTH, LDS_BYTES, stream>>>(pulse, d1w, d1b, d2w, d2b,
                                                 Wih, Whh, bih, bhh, emb, out);
}

// Round 4
// 796.739 us; speedup vs baseline: 23.8869x; 23.8869x over previous
//
#include <hip/hip_runtime.h>
#include <math.h>

// GRU: C=64, L=2, B=2048, SEQ=512, DEC=35.
// Per block: BT=8 batch rows. 768 threads = 12 waves; wave w owns output
// N-tile (16 gate columns) w for ALL phases, with B-fragments (weights)
// preconverted to bf16 and held in VGPRs for the whole kernel.
//
// Stacked block-diagonal matmuls, one [16,128]@[128,192] per phase:
//   phase A: A = [x(8) over k<64 ; h0(8) over k>=64], B = [Wih0 ; Whh0]
//            -> C rows 0-7 = gi0 (used in decoder), rows 8-15 = gh0
//   phase C: A = [h0new ; h1],   B = [Wih1 ; Whh1]
//            -> C rows 0-7 = gi1, rows 8-15 = gh1
// Zeros in the off-diagonal A blocks are never written (staged LDS zeroed once).
//
// MFMA 16x16x32 bf16. A/B share one (group,elem)->k convention, so any
// hardware k-permutation cancels. C/D: col=lane&15, row=(lane>>4)*4+reg
// (HW-verified mapping, learn_hip m89).
//
// h recurrence (z-blend) stays f32 in registers of the nonlinearity threads;
// bf16 only enters MFMA operands.

#define CCH  64
#define GG   192
#define SEQ  512
#define DECS 35
#define BT   8
#define NTH  768
#define PSTR 194          // pre row stride (f32): 194 mod 32 = 2 -> 2-way (free) C stores
#define STG_ELEMS (16 * 17 * 8)   // [sg 0..15][row 0..16][e 0..7] bf16, row-padded to 17

typedef __attribute__((ext_vector_type(8))) short bf16x8;
typedef __attribute__((ext_vector_type(4))) float f32x4;

__device__ __forceinline__ short f2b(float f) {   // f32 -> bf16 RNE
  union { float f; unsigned u; } v; v.f = f;
  unsigned r = v.u + 0x7fffu + ((v.u >> 16) & 1u);
  return (short)(r >> 16);
}
__device__ __forceinline__ float sigf(float x) { return 1.0f / (1.0f + __expf(-x)); }
__device__ __forceinline__ float tanhfast(float x) {
  float t = __expf(-2.0f * fabsf(x));
  float r = (1.0f - t) / (1.0f + t);
  return copysignf(r, x);
}
// stage element index for logical (row, k)
__device__ __forceinline__ int stoff(int row, int k) {
  return ((k >> 3) * 17 + row) * 8 + (k & 7);
}

extern "C" __global__ void __launch_bounds__(NTH, 1)
gru_mfma(const float* __restrict__ pulse,   // [B,512,2]
         const float* __restrict__ d1w,     // [64,2]
         const float* __restrict__ d1b,     // [64]
         const float* __restrict__ d2w,     // [2,64]
         const float* __restrict__ d2b,     // [2]
         const float* __restrict__ Wih,     // [2,192,64]
         const float* __restrict__ Whh,     // [2,192,64]
         const float* __restrict__ bih,     // [2,192]
         const float* __restrict__ bhh,     // [2,192]
         const float* __restrict__ embed,   // [1,64]
         float* __restrict__ out)           // [B,35,2]
{
  __shared__ __align__(16) unsigned short stA[STG_ELEMS];  // phase-A operand stage
  __shared__ __align__(16) unsigned short stC[STG_ELEMS];  // phase-C operand stage
  __shared__ float pre[16 * PSTR];                         // gate pre-activations

  const int tid = threadIdx.x;
  const int wid = tid >> 6;        // 0..11 == N-tile index
  const int l   = tid & 63;
  const int lm  = l & 15;          // m/n index (A rows / B cols / C cols)
  const int lg  = l >> 4;          // k-group
  const int nb  = wid * 16;        // tile's first gate column
  const int bgb = blockIdx.x * BT;

  // ---- zero stages (off-diagonal A blocks must be 0, and stay 0 forever)
  for (int i = tid; i < STG_ELEMS; i += NTH) { stA[i] = 0; stC[i] = 0; }

  // ---- preload B-fragments (weights) into registers, bf16
  const float* Wih0 = Wih;
  const float* Whh0 = Whh;
  const float* Wih1 = Wih + GG * CCH;
  const float* Whh1 = Whh + GG * CCH;
  bf16x8 bA[4], bC[4];
  {
    const int n = nb + lm;   // gate column this lane supplies
#pragma unroll
    for (int s = 0; s < 4; ++s) {
#pragma unroll
      for (int e = 0; e < 8; ++e) {
        int kk = 32 * s + 8 * lg + e;
        float va = (kk < 64) ? Wih0[n * CCH + kk] : Whh0[n * CCH + kk - 64];
        float vc = (kk < 64) ? Wih1[n * CCH + kk] : Whh1[n * CCH + kk - 64];
        bA[s][e] = f2b(va);
        bC[s][e] = f2b(vc);
      }
    }
  }

  // ---- nonlinearity-thread state (tid<512): thread = (row rr, channel c)
  const int rr = tid >> 6;         // == wid; batch row for tid<512
  const int c  = tid & 63;
  float A0[3], A1[3], C0[3], bi0[3], bh0[3], bi1[3], bh1[3];
  float h0 = 0.f, h1 = 0.f;
  float w20 = 0.f, w21 = 0.f, ob0 = 0.f, ob1 = 0.f;
  if (tid < 512) {
    // fold dense1 into layer0 input gates: gi0 = p0*A0 + p1*A1 + C0 (exact f32)
#pragma unroll
    for (int j = 0; j < 3; ++j) {
      int g = c + 64 * j;          // r, z, n gate rows for channel c
      float a0 = 0.f, a1 = 0.f, cc = 0.f;
      for (int k = 0; k < CCH; ++k) {
        float wv = Wih0[g * CCH + k];
        a0 += wv * d1w[2 * k];
        a1 += wv * d1w[2 * k + 1];
        cc += wv * d1b[k];
      }
      A0[j] = a0; A1[j] = a1; C0[j] = cc + bih[g];
      bi0[j] = bih[g];        bh0[j] = bhh[g];
      bi1[j] = bih[GG + g];   bh1[j] = bhh[GG + g];
    }
    w20 = d2w[c]; w21 = d2w[CCH + c];
    ob0 = d2b[0]; ob1 = d2b[1];
  }
  __syncthreads();

  // ---- per-phase helpers
  auto phaseA = [&]() {
    f32x4 acc = {0.f, 0.f, 0.f, 0.f};
#pragma unroll
    for (int s = 0; s < 4; ++s) {
      bf16x8 af = *(const bf16x8*)&stA[((s * 4 + lg) * 17 + lm) * 8];
      acc = __builtin_amdgcn_mfma_f32_16x16x32_bf16(af, bA[s], acc, 0, 0, 0);
    }
#pragma unroll
    for (int r = 0; r < 4; ++r) pre[(lg * 4 + r) * PSTR + nb + lm] = acc[r];
  };
  auto phaseC = [&]() {
    f32x4 acc = {0.f, 0.f, 0.f, 0.f};
#pragma unroll
    for (int s = 0; s < 4; ++s) {
      bf16x8 af = *(const bf16x8*)&stC[((s * 4 + lg) * 17 + lm) * 8];
      acc = __builtin_amdgcn_mfma_f32_16x16x32_bf16(af, bC[s], acc, 0, 0, 0);
    }
#pragma unroll
    for (int r = 0; r < 4; ++r) pre[(lg * 4 + r) * PSTR + nb + lm] = acc[r];
  };
  // layer-1 cell + staging writes; dec: also dense2 head
  auto nonlinL1 = [&](bool dec, int d) {
    if (tid < 512) {
      float gR = pre[rr * PSTR + c]       + bi1[0] + pre[(8 + rr) * PSTR + c]       + bh1[0];
      float gZ = pre[rr * PSTR + 64 + c]  + bi1[1] + pre[(8 + rr) * PSTR + 64 + c]  + bh1[1];
      float gi = pre[rr * PSTR + 128 + c] + bi1[2];
      float gh = pre[(8 + rr) * PSTR + 128 + c] + bh1[2];
      float r = sigf(gR), z = sigf(gZ);
      float nn = tanhfast(gi + r * gh);
      h1 = (1.f - z) * nn + z * h1;
      short hb = f2b(h1);
      stA[stoff(rr, c)] = hb;            // x-slot for next phase A (decoder input)
      stC[stoff(8 + rr, 64 + c)] = hb;   // h1-slot for next phase C
      if (dec) {
        float o0 = h1 * w20, o1 = h1 * w21;
#pragma unroll
        for (int off = 32; off >= 1; off >>= 1) {
          o0 += __shfl_xor(o0, off);
          o1 += __shfl_xor(o1, off);
        }
        if (c == 0) {
          out[((size_t)(bgb + rr) * DECS + d) * 2 + 0] = o0 + ob0;
          out[((size_t)(bgb + rr) * DECS + d) * 2 + 1] = o1 + ob1;
        }
      }
    }
  };

  // ======================= encoder: 512 steps =======================
  const float* prow = pulse + (size_t)(bgb + (rr & 7)) * SEQ * 2;
  for (int t = 0; t < SEQ; ++t) {
    float2 pv = make_float2(0.f, 0.f);
    if (tid < 512) pv = *(const float2*)(prow + t * 2);   // hides under phase A

    phaseA();                 // C rows 8-15 = gh0 (rows 0-7 garbage, ignored)
    __syncthreads();

    if (tid < 512) {          // layer0 cell: gi0 from exact rank-2 fold
      float giR = pv.x * A0[0] + pv.y * A1[0] + C0[0];
      float giZ = pv.x * A0[1] + pv.y * A1[1] + C0[1];
      float giN = pv.x * A0[2] + pv.y * A1[2] + C0[2];
      float gR = giR + pre[(8 + rr) * PSTR + c]       + bh0[0];
      float gZ = giZ + pre[(8 + rr) * PSTR + 64 + c]  + bh0[1];
      float gh = pre[(8 + rr) * PSTR + 128 + c] + bh0[2];
      float r = sigf(gR), z = sigf(gZ);
      float nn = tanhfast(giN + r * gh);
      h0 = (1.f - z) * nn + z * h0;
      short hb = f2b(h0);
      stC[stoff(rr, c)] = hb;            // h0new -> phase C rows 0-7
      stA[stoff(8 + rr, 64 + c)] = hb;   // h0new -> next phase A rows 8-15
    }
    __syncthreads();

    phaseC();                 // rows 0-7 = gi1, rows 8-15 = gh1
    __syncthreads();

    nonlinL1(false, 0);
    __syncthreads();
  }

  // ---- seed decoder input with embedding
  if (tid < 512) stA[stoff(rr, c)] = f2b(embed[c]);
  __syncthreads();

  // ======================= decoder: 35 steps =======================
  for (int d = 0; d < DECS; ++d) {
    phaseA();                 // rows 0-7 = gi0 (x = embed / prev top), 8-15 = gh0
    __syncthreads();

    if (tid < 512) {          // layer0 cell: gi0 from MFMA
      float gR = pre[rr * PSTR + c]       + bi0[0] + pre[(8 + rr) * PSTR + c]       + bh0[0];
      float gZ = pre[rr * PSTR + 64 + c]  + bi0[1] + pre[(8 + rr) * PSTR + 64 + c]  + bh0[1];
      float gi = pre[rr * PSTR + 128 + c] + bi0[2];
      float gh = pre[(8 + rr) * PSTR + 128 + c] + bh0[2];
      float r = sigf(gR), z = sigf(gZ);
      float nn = tanhfast(gi + r * gh);
      h0 = (1.f - z) * nn + z * h0;
      short hb = f2b(h0);
      stC[stoff(rr, c)] = hb;
      stA[stoff(8 + rr, 64 + c)] = hb;
    }
    __syncthreads();

    phaseC();
    __syncthreads();

    nonlinL1(true, d);
    __syncthreads();
  }
}

extern "C" void kernel_launch(void* const* d_in, const int* in_sizes, int n_in,
                              void* d_out, int out_size, void* d_ws, size_t ws_size,
                              hipStream_t stream) {
  const float* pulse = (const float*)d_in[0];
  const float* d1w   = (const float*)d_in[1];
  const float* d1b   = (const float*)d_in[2];
  const float* d2w   = (const float*)d_in[3];
  const float* d2b   = (const float*)d_in[4];
  const float* Wih   = (const float*)d_in[5];
  const float* Whh   = (const float*)d_in[6];
  const float* bih   = (const float*)d_in[7];
  const float* bhh   = (const float*)d_in[8];
  const float* emb   = (const float*)d_in[9];
  float* out = (float*)d_out;

  int B = in_sizes[0] / (SEQ * 2);   // 2048
  gru_mfma<<<B / BT, NTH, 0, stream>>>(pulse, d1w, d1b, d2w, d2b,
                                       Wih, Whh, bih, bhh, emb, out);
}